// Round 4
// baseline (2077.042 us; speedup 1.0000x reference)
//
#include <hip/hip_runtime.h>

#define NN 100000
#define NE 3200000
#define NG 256
#define H 32
#define CE 8                     // edges per thread chunk
#define NCH (NE / CE)            // 400000 chunks
#define SB ((NN + 255) / 256)    // 391 scan blocks

// Monotone bijection float -> u32 (order-preserving), so u32 max == float max.
__device__ __forceinline__ unsigned encf(float f) {
    unsigned u = __float_as_uint(f);
    return (u & 0x80000000u) ? ~u : (u | 0x80000000u);
}
__device__ __forceinline__ float decf(unsigned u) {
    return __uint_as_float((u & 0x80000000u) ? (u & 0x7fffffffu) : ~u);
}

// Flush a register-held run max to global agg (enc domain, test-before-atomic).
// agg starts at enc(0): values <=0 never pass the test (folds relu + neginf fill).
__device__ __forceinline__ void flush_row(unsigned* __restrict__ agg, int node,
                                          const float* m) {
    unsigned* ag = agg + (size_t)node * H;
#pragma unroll
    for (int r = 0; r < 8; r++) {
        uint4 c = ((const uint4*)ag)[r];
        unsigned v0 = encf(m[4 * r + 0]);
        unsigned v1 = encf(m[4 * r + 1]);
        unsigned v2 = encf(m[4 * r + 2]);
        unsigned v3 = encf(m[4 * r + 3]);
        if (v0 > c.x) atomicMax(ag + 4 * r + 0, v0);
        if (v1 > c.y) atomicMax(ag + 4 * r + 1, v1);
        if (v2 > c.z) atomicMax(ag + 4 * r + 2, v2);
        if (v3 > c.w) atomicMax(ag + 4 * r + 3, v3);
    }
}

// init agg=enc(0), g=enc(0), hist=0. Grid covers NN*H = 3.2M.
__global__ __launch_bounds__(256) void k_init(unsigned* __restrict__ agg,
                                              unsigned* __restrict__ g,
                                              unsigned* __restrict__ hist) {
    int i = blockIdx.x * 256 + threadIdx.x;
    agg[i] = 0x80000000u;
    if (i < NG * H) g[i] = 0x80000000u;
    if (i < NN) hist[i] = 0u;
}

__global__ __launch_bounds__(256) void k_hist(const int* __restrict__ dst,
                                              unsigned* __restrict__ hist) {
    int e = blockIdx.x * 256 + threadIdx.x;   // grid covers exactly NE
    atomicAdd(&hist[dst[e]], 1u);
}

// Block-level exclusive scan (Hillis-Steele in LDS), 256 elems/block.
__global__ __launch_bounds__(256) void k_scan1(const unsigned* __restrict__ hist,
                                               unsigned* __restrict__ pre,
                                               unsigned* __restrict__ bsum) {
    __shared__ unsigned sd[256];
    int tid = threadIdx.x;
    int i = blockIdx.x * 256 + tid;
    unsigned v = (i < NN) ? hist[i] : 0u;
    sd[tid] = v;
    __syncthreads();
    for (int off = 1; off < 256; off <<= 1) {
        unsigned t = (tid >= off) ? sd[tid - off] : 0u;
        __syncthreads();
        sd[tid] += t;
        __syncthreads();
    }
    if (i < NN) pre[i] = sd[tid] - v;
    if (tid == 255) bsum[blockIdx.x] = sd[255];
}

__global__ __launch_bounds__(512) void k_scan2(const unsigned* __restrict__ bsum,
                                               unsigned* __restrict__ bpre) {
    __shared__ unsigned sd[512];
    int t = threadIdx.x;
    unsigned v = (t < SB) ? bsum[t] : 0u;
    sd[t] = v;
    __syncthreads();
    for (int off = 1; off < 512; off <<= 1) {
        unsigned x = (t >= off) ? sd[t - off] : 0u;
        __syncthreads();
        sd[t] += x;
        __syncthreads();
    }
    if (t < SB) bpre[t] = sd[t] - v;
}

// cursors[i] = global exclusive prefix (scatter cursor); ends[i] = prefix+count.
__global__ __launch_bounds__(256) void k_scan3(const unsigned* __restrict__ pre,
                                               const unsigned* __restrict__ bpre,
                                               const unsigned* __restrict__ hist,
                                               unsigned* __restrict__ cursors,
                                               unsigned* __restrict__ ends) {
    int i = blockIdx.x * 256 + threadIdx.x;
    if (i < NN) {
        unsigned o = pre[i] + bpre[blockIdx.x];
        cursors[i] = o;
        ends[i] = o + hist[i];
    }
}

// Scatter src ids into dst-sorted order (order within a run is nondeterministic
// but max-reduction is order-free).
__global__ __launch_bounds__(256) void k_scatter(const int* __restrict__ src,
                                                 const int* __restrict__ dst,
                                                 unsigned* __restrict__ cursors,
                                                 unsigned* __restrict__ srcS) {
    int e = blockIdx.x * 256 + threadIdx.x;   // grid covers exactly NE
    int d = dst[e];
    unsigned slot = atomicAdd(&cursors[d], 1u);
    srcS[slot] = (unsigned)src[e];
}

// chunk_node[c] = dst node owning edge c*CE = smallest n with ends[n] > c*CE.
// Binary search over hot (L2-resident) ends[]; replaces 3.2M atomicMin.
__global__ __launch_bounds__(256) void k_chunks(const unsigned* __restrict__ ends,
                                                unsigned* __restrict__ chunk_node) {
    int c = blockIdx.x * 256 + threadIdx.x;
    if (c >= NCH) return;
    unsigned target = (unsigned)c * CE;
    int lo = 0, hi = NN - 1;
    while (lo < hi) {
        int mid = (lo + hi) >> 1;
        if (ends[mid] <= target) lo = mid + 1; else hi = mid;
    }
    chunk_node[c] = (unsigned)lo;
}

// Layer-1 edge kernel: 8 dst-sorted edges/thread, register run-max.
// Streaming-j matvec: t_j never materialized as an array (live set ~100 VGPR).
__global__ __launch_bounds__(256, 2) void k_edge1(const unsigned* __restrict__ srcS,
                                                  const unsigned* __restrict__ ends,
                                                  const unsigned* __restrict__ chunk_node,
                                                  const float* __restrict__ pos,
                                                  const float* __restrict__ W1a,
                                                  const float* __restrict__ b1a,
                                                  const float* __restrict__ W1b,
                                                  const float* __restrict__ b1b,
                                                  unsigned* __restrict__ agg) {
    int gid = blockIdx.x * 256 + threadIdx.x;
    if (gid >= NCH) return;
    unsigned base = (unsigned)gid * CE;
    int cur = (int)chunk_node[gid];
    unsigned end_cur = ends[cur];
    float pd0 = pos[3 * cur], pd1 = pos[3 * cur + 1], pd2 = pos[3 * cur + 2];
    float macc[H];
#pragma unroll
    for (int k = 0; k < H; k++) macc[k] = 0.f;
    for (int c = 0; c < CE; c++) {   // rolled: keeps body in I$
        unsigned e = base + c;
        if (e >= end_cur) {
            flush_row(agg, cur, macc);
            do { cur++; end_cur = ends[cur]; } while (e >= end_cur);
            pd0 = pos[3 * cur]; pd1 = pos[3 * cur + 1]; pd2 = pos[3 * cur + 2];
#pragma unroll
            for (int k = 0; k < H; k++) macc[k] = 0.f;
        }
        int s = (int)srcS[e];
        float ps0 = pos[3 * s], ps1 = pos[3 * s + 1], ps2 = pos[3 * s + 2];
        float e0 = ps0 - pd0, e1 = ps1 - pd1, e2 = ps2 - pd2;
        float m[H];
#pragma unroll
        for (int k = 0; k < H; k++) m[k] = b1b[k];
#pragma unroll
        for (int j = 0; j < H; j++) {
            float t = b1a[j];
            t = fmaf(ps0, W1a[j], t);
            t = fmaf(ps1, W1a[32 + j], t);
            t = fmaf(ps2, W1a[64 + j], t);
            t = fmaf(e0, W1a[96 + j], t);
            t = fmaf(e1, W1a[128 + j], t);
            t = fmaf(e2, W1a[160 + j], t);
            t = fmaxf(t, 0.f);
#pragma unroll
            for (int k = 0; k < H; k++) m[k] = fmaf(t, W1b[j * H + k], m[k]);
        }
#pragma unroll
        for (int k = 0; k < H; k++) macc[k] = fmaxf(macc[k], m[k]);
    }
    flush_row(agg, cur, macc);
}

// Layer-2 node precompute: E2[n] = b2a + h[n]@W2a[0:32] + pos[n]@W2a[32:35];
// also resets agg row for reuse by layer 2 (each thread owns its row).
__global__ __launch_bounds__(256) void k_pre2(const float* __restrict__ pos,
                                              unsigned* __restrict__ agg,
                                              const float* __restrict__ W2a,
                                              const float* __restrict__ b2a,
                                              float* __restrict__ E2) {
    int n = blockIdx.x * 256 + threadIdx.x;
    if (n >= NN) return;
    float h[H];
    uint4* A4 = (uint4*)(agg + (size_t)n * H);
#pragma unroll
    for (int r = 0; r < 8; r++) {
        uint4 u = A4[r];
        h[4 * r + 0] = decf(u.x);
        h[4 * r + 1] = decf(u.y);
        h[4 * r + 2] = decf(u.z);
        h[4 * r + 3] = decf(u.w);
        A4[r] = make_uint4(0x80000000u, 0x80000000u, 0x80000000u, 0x80000000u);
    }
    float p0 = pos[3 * n], p1 = pos[3 * n + 1], p2 = pos[3 * n + 2];
    float ev[H];
#pragma unroll
    for (int k = 0; k < H; k++) {
        float v = b2a[k];
        v = fmaf(p0, W2a[32 * H + k], v);
        v = fmaf(p1, W2a[33 * H + k], v);
        v = fmaf(p2, W2a[34 * H + k], v);
        ev[k] = v;
    }
#pragma unroll
    for (int j = 0; j < H; j++) {
        float hj = h[j];
#pragma unroll
        for (int k = 0; k < H; k++) ev[k] = fmaf(hj, W2a[j * H + k], ev[k]);
    }
    float4* E4 = (float4*)(E2 + (size_t)n * H);
#pragma unroll
    for (int r = 0; r < 8; r++)
        E4[r] = make_float4(ev[4 * r], ev[4 * r + 1], ev[4 * r + 2], ev[4 * r + 3]);
}

// Layer-2 edge kernel: t_j = relu(E2[src][j] - pd@W2a[32:35][j]) streamed into
// m[32]; dst-term recomputed inline (+3 FMA/j) to keep live set ~100 VGPR.
__global__ __launch_bounds__(256, 2) void k_edge2(const unsigned* __restrict__ srcS,
                                                  const unsigned* __restrict__ ends,
                                                  const unsigned* __restrict__ chunk_node,
                                                  const float* __restrict__ pos,
                                                  const float* __restrict__ E2,
                                                  const float* __restrict__ W2a,
                                                  const float* __restrict__ W2b,
                                                  const float* __restrict__ b2b,
                                                  unsigned* __restrict__ agg) {
    int gid = blockIdx.x * 256 + threadIdx.x;
    if (gid >= NCH) return;
    unsigned base = (unsigned)gid * CE;
    int cur = (int)chunk_node[gid];
    unsigned end_cur = ends[cur];
    float pd0 = pos[3 * cur], pd1 = pos[3 * cur + 1], pd2 = pos[3 * cur + 2];
    float macc[H];
#pragma unroll
    for (int k = 0; k < H; k++) macc[k] = 0.f;
    for (int c = 0; c < CE; c++) {
        unsigned e = base + c;
        if (e >= end_cur) {
            flush_row(agg, cur, macc);
            do { cur++; end_cur = ends[cur]; } while (e >= end_cur);
            pd0 = pos[3 * cur]; pd1 = pos[3 * cur + 1]; pd2 = pos[3 * cur + 2];
#pragma unroll
            for (int k = 0; k < H; k++) macc[k] = 0.f;
        }
        int s = (int)srcS[e];
        const float4* er = (const float4*)(E2 + (size_t)s * H);
        float m[H];
#pragma unroll
        for (int k = 0; k < H; k++) m[k] = b2b[k];
#pragma unroll
        for (int r = 0; r < 8; r++) {
            float4 e4 = er[r];
#pragma unroll
            for (int q = 0; q < 4; q++) {
                int j = 4 * r + q;
                float ej = (q == 0) ? e4.x : (q == 1) ? e4.y : (q == 2) ? e4.z : e4.w;
                float w = fmaf(pd0, W2a[32 * H + j],
                          fmaf(pd1, W2a[33 * H + j], pd2 * W2a[34 * H + j]));
                float t = fmaxf(ej - w, 0.f);
#pragma unroll
                for (int k = 0; k < H; k++) m[k] = fmaf(t, W2b[j * H + k], m[k]);
            }
        }
#pragma unroll
        for (int k = 0; k < H; k++) macc[k] = fmaxf(macc[k], m[k]);
    }
    flush_row(agg, cur, macc);
}

// Graph max-pool (encoded domain; max commutes with monotone encoding).
__global__ __launch_bounds__(256) void k_pool(const unsigned* __restrict__ agg,
                                              const int* __restrict__ batch,
                                              unsigned* __restrict__ g) {
    int n = blockIdx.x * 256 + threadIdx.x;
    if (n >= NN) return;
    int bidx = batch[n];
    unsigned* gb = g + (size_t)bidx * H;
    const uint4* A4 = (const uint4*)(agg + (size_t)n * H);
#pragma unroll
    for (int r = 0; r < 8; r++) {
        uint4 v = A4[r];
        uint4 c = ((const uint4*)gb)[r];
        if (v.x > c.x) atomicMax(gb + 4 * r + 0, v.x);
        if (v.y > c.y) atomicMax(gb + 4 * r + 1, v.y);
        if (v.z > c.z) atomicMax(gb + 4 * r + 2, v.z);
        if (v.w > c.w) atomicMax(gb + 4 * r + 3, v.w);
    }
}

__global__ __launch_bounds__(256) void k_out(const unsigned* __restrict__ g,
                                             const float* __restrict__ Wout,
                                             const float* __restrict__ bout,
                                             float* __restrict__ out) {
    int bidx = threadIdx.x;  // one block of 256
    float acc = bout[0];
#pragma unroll
    for (int k = 0; k < H; k++) acc = fmaf(decf(g[bidx * H + k]), Wout[k], acc);
    out[bidx] = acc;
}

extern "C" void kernel_launch(void* const* d_in, const int* in_sizes, int n_in,
                              void* d_out, int out_size, void* d_ws, size_t ws_size,
                              hipStream_t stream) {
    const float* pos  = (const float*)d_in[0];
    const int* src    = (const int*)d_in[1];
    const int* dst    = src + NE;
    const int* batch  = (const int*)d_in[2];
    const float* W1a  = (const float*)d_in[3];
    const float* b1a  = (const float*)d_in[4];
    const float* W1b  = (const float*)d_in[5];
    const float* b1b  = (const float*)d_in[6];
    const float* W2a  = (const float*)d_in[7];
    const float* b2a  = (const float*)d_in[8];
    const float* W2b  = (const float*)d_in[9];
    const float* b2b  = (const float*)d_in[10];
    const float* Wout = (const float*)d_in[11];
    const float* bout = (const float*)d_in[12];
    float* out = (float*)d_out;

    const size_t SZ = (size_t)NN * H;  // 3.2M words
    unsigned* agg        = (unsigned*)d_ws;          // 12.8 MB
    float*    E2         = (float*)d_ws + SZ;        // 12.8 MB (aliased pre-edge1)
    unsigned* srcS       = (unsigned*)d_ws + 2 * SZ; // 12.8 MB (dst-sorted src ids)
    unsigned* g          = (unsigned*)d_ws + 3 * SZ; // 32 KB
    unsigned* ends       = g + NG * H;               // 400 KB (CSR run ends)
    unsigned* chunk_node = ends + NN;                // 1.6 MB (first dst per chunk)
    unsigned* bsum       = chunk_node + NCH;         // scan partials
    unsigned* bpre       = bsum + SB + 1;
    // Sort-phase temporaries aliased into E2's space (dead before k_pre2 writes):
    unsigned* hist    = (unsigned*)E2;
    unsigned* pre     = hist + NN;
    unsigned* cursors = pre + NN;

    const int EDGE_BLOCKS  = NE / 256;          // 12500
    const int INIT_BLOCKS  = (NN * H) / 256;    // 12500
    const int NODE_BLOCKS  = SB;                // 391
    const int CHUNK_BLOCKS = (NCH + 255) / 256; // 1563

    k_init<<<INIT_BLOCKS, 256, 0, stream>>>(agg, g, hist);
    k_hist<<<EDGE_BLOCKS, 256, 0, stream>>>(dst, hist);
    k_scan1<<<NODE_BLOCKS, 256, 0, stream>>>(hist, pre, bsum);
    k_scan2<<<1, 512, 0, stream>>>(bsum, bpre);
    k_scan3<<<NODE_BLOCKS, 256, 0, stream>>>(pre, bpre, hist, cursors, ends);
    k_scatter<<<EDGE_BLOCKS, 256, 0, stream>>>(src, dst, cursors, srcS);
    k_chunks<<<CHUNK_BLOCKS, 256, 0, stream>>>(ends, chunk_node);
    k_edge1<<<CHUNK_BLOCKS, 256, 0, stream>>>(srcS, ends, chunk_node, pos,
                                              W1a, b1a, W1b, b1b, agg);
    k_pre2<<<NODE_BLOCKS, 256, 0, stream>>>(pos, agg, W2a, b2a, E2);
    k_edge2<<<CHUNK_BLOCKS, 256, 0, stream>>>(srcS, ends, chunk_node, pos, E2,
                                              W2a, W2b, b2b, agg);
    k_pool<<<NODE_BLOCKS, 256, 0, stream>>>(agg, batch, g);
    k_out<<<1, 256, 0, stream>>>(g, Wout, bout, out);
}

// Round 5
// 1866.719 us; speedup vs baseline: 1.1127x; 1.1127x over previous
//
#include <hip/hip_runtime.h>

#define NN 100000
#define NE 3200000
#define NG 256
#define H 32
#define CE 8                     // edges per thread chunk
#define NCH (NE / CE)            // 400000 chunks
#define SB ((NN + 255) / 256)    // 391 scan blocks

// Monotone bijection float -> u32 (order-preserving), so u32 max == float max.
__device__ __forceinline__ unsigned encf(float f) {
    unsigned u = __float_as_uint(f);
    return (u & 0x80000000u) ? ~u : (u | 0x80000000u);
}
__device__ __forceinline__ float decf(unsigned u) {
    return __uint_as_float((u & 0x80000000u) ? (u & 0x7fffffffu) : ~u);
}

// Flush a 16-wide register run-max to global agg (enc domain, test-before-atomic).
// agg starts at enc(0): values <=0 never pass the test (folds relu + neginf fill).
__device__ __forceinline__ void flush_half(unsigned* __restrict__ agg, int node,
                                           int hb, const float* m) {
    unsigned* ag = agg + (size_t)node * H + hb * 16;
#pragma unroll
    for (int r = 0; r < 4; r++) {
        uint4 c = ((const uint4*)ag)[r];
        unsigned v0 = encf(m[4 * r + 0]);
        unsigned v1 = encf(m[4 * r + 1]);
        unsigned v2 = encf(m[4 * r + 2]);
        unsigned v3 = encf(m[4 * r + 3]);
        if (v0 > c.x) atomicMax(ag + 4 * r + 0, v0);
        if (v1 > c.y) atomicMax(ag + 4 * r + 1, v1);
        if (v2 > c.z) atomicMax(ag + 4 * r + 2, v2);
        if (v3 > c.w) atomicMax(ag + 4 * r + 3, v3);
    }
}

// init agg=enc(0), g=enc(0), hist=0. Grid covers NN*H = 3.2M.
__global__ __launch_bounds__(256) void k_init(unsigned* __restrict__ agg,
                                              unsigned* __restrict__ g,
                                              unsigned* __restrict__ hist) {
    int i = blockIdx.x * 256 + threadIdx.x;
    agg[i] = 0x80000000u;
    if (i < NG * H) g[i] = 0x80000000u;
    if (i < NN) hist[i] = 0u;
}

__global__ __launch_bounds__(256) void k_hist(const int* __restrict__ dst,
                                              unsigned* __restrict__ hist) {
    int e = blockIdx.x * 256 + threadIdx.x;   // grid covers exactly NE
    atomicAdd(&hist[dst[e]], 1u);
}

// Block-level exclusive scan (Hillis-Steele in LDS), 256 elems/block.
__global__ __launch_bounds__(256) void k_scan1(const unsigned* __restrict__ hist,
                                               unsigned* __restrict__ pre,
                                               unsigned* __restrict__ bsum) {
    __shared__ unsigned sd[256];
    int tid = threadIdx.x;
    int i = blockIdx.x * 256 + tid;
    unsigned v = (i < NN) ? hist[i] : 0u;
    sd[tid] = v;
    __syncthreads();
    for (int off = 1; off < 256; off <<= 1) {
        unsigned t = (tid >= off) ? sd[tid - off] : 0u;
        __syncthreads();
        sd[tid] += t;
        __syncthreads();
    }
    if (i < NN) pre[i] = sd[tid] - v;
    if (tid == 255) bsum[blockIdx.x] = sd[255];
}

__global__ __launch_bounds__(512) void k_scan2(const unsigned* __restrict__ bsum,
                                               unsigned* __restrict__ bpre) {
    __shared__ unsigned sd[512];
    int t = threadIdx.x;
    unsigned v = (t < SB) ? bsum[t] : 0u;
    sd[t] = v;
    __syncthreads();
    for (int off = 1; off < 512; off <<= 1) {
        unsigned x = (t >= off) ? sd[t - off] : 0u;
        __syncthreads();
        sd[t] += x;
        __syncthreads();
    }
    if (t < SB) bpre[t] = sd[t] - v;
}

// cursors[i] = global exclusive prefix (scatter cursor); ends[i] = prefix+count.
__global__ __launch_bounds__(256) void k_scan3(const unsigned* __restrict__ pre,
                                               const unsigned* __restrict__ bpre,
                                               const unsigned* __restrict__ hist,
                                               unsigned* __restrict__ cursors,
                                               unsigned* __restrict__ ends) {
    int i = blockIdx.x * 256 + threadIdx.x;
    if (i < NN) {
        unsigned o = pre[i] + bpre[blockIdx.x];
        cursors[i] = o;
        ends[i] = o + hist[i];
    }
}

// Scatter src ids into dst-sorted order (order within a run is nondeterministic
// but max-reduction is order-free).
__global__ __launch_bounds__(256) void k_scatter(const int* __restrict__ src,
                                                 const int* __restrict__ dst,
                                                 unsigned* __restrict__ cursors,
                                                 unsigned* __restrict__ srcS) {
    int e = blockIdx.x * 256 + threadIdx.x;   // grid covers exactly NE
    int d = dst[e];
    unsigned slot = atomicAdd(&cursors[d], 1u);
    srcS[slot] = (unsigned)src[e];
}

// chunk_node[c] = dst node owning edge c*CE = smallest n with ends[n] > c*CE.
__global__ __launch_bounds__(256) void k_chunks(const unsigned* __restrict__ ends,
                                                unsigned* __restrict__ chunk_node) {
    int c = blockIdx.x * 256 + threadIdx.x;
    if (c >= NCH) return;
    unsigned target = (unsigned)c * CE;
    int lo = 0, hi = NN - 1;
    while (lo < hi) {
        int mid = (lo + hi) >> 1;
        if (ends[mid] <= target) lo = mid + 1; else hi = mid;
    }
    chunk_node[c] = (unsigned)lo;
}

// Layer-1 edge kernel: two sequential 16-output half-passes over this thread's
// 8 dst-sorted edges. Live set per half ~50 VGPR -> fits the 8-wave/SIMD
// (64 VGPR) allocation with no spill. t_j recomputed per half (+7 ops/j).
__global__ __launch_bounds__(256) void k_edge1(const unsigned* __restrict__ srcS,
                                               const unsigned* __restrict__ ends,
                                               const unsigned* __restrict__ chunk_node,
                                               const float* __restrict__ pos,
                                               const float* __restrict__ W1a,
                                               const float* __restrict__ b1a,
                                               const float* __restrict__ W1b,
                                               const float* __restrict__ b1b,
                                               unsigned* __restrict__ agg) {
    int gid = blockIdx.x * 256 + threadIdx.x;
    if (gid >= NCH) return;
    unsigned base = (unsigned)gid * CE;
#pragma unroll 1
    for (int hb = 0; hb < 2; hb++) {           // MUST stay rolled: halves serial
        int cur = (int)chunk_node[gid];
        unsigned end_cur = ends[cur];
        float pd0 = pos[3 * cur], pd1 = pos[3 * cur + 1], pd2 = pos[3 * cur + 2];
        float macc[16];
#pragma unroll
        for (int k = 0; k < 16; k++) macc[k] = 0.f;
#pragma unroll 1
        for (int c = 0; c < CE; c++) {
            unsigned e = base + c;
            if (e >= end_cur) {
                flush_half(agg, cur, hb, macc);
                do { cur++; end_cur = ends[cur]; } while (e >= end_cur);
                pd0 = pos[3 * cur]; pd1 = pos[3 * cur + 1]; pd2 = pos[3 * cur + 2];
#pragma unroll
                for (int k = 0; k < 16; k++) macc[k] = 0.f;
            }
            int s = (int)srcS[e];
            float ps0 = pos[3 * s], ps1 = pos[3 * s + 1], ps2 = pos[3 * s + 2];
            float e0 = ps0 - pd0, e1 = ps1 - pd1, e2 = ps2 - pd2;
            float m[16];
#pragma unroll
            for (int k = 0; k < 16; k++) m[k] = b1b[hb * 16 + k];
#pragma unroll
            for (int j = 0; j < H; j++) {
                float t = b1a[j];
                t = fmaf(ps0, W1a[j], t);
                t = fmaf(ps1, W1a[32 + j], t);
                t = fmaf(ps2, W1a[64 + j], t);
                t = fmaf(e0, W1a[96 + j], t);
                t = fmaf(e1, W1a[128 + j], t);
                t = fmaf(e2, W1a[160 + j], t);
                t = fmaxf(t, 0.f);
#pragma unroll
                for (int k = 0; k < 16; k++)
                    m[k] = fmaf(t, W1b[j * H + hb * 16 + k], m[k]);
            }
#pragma unroll
            for (int k = 0; k < 16; k++) macc[k] = fmaxf(macc[k], m[k]);
        }
        flush_half(agg, cur, hb, macc);
    }
}

// Layer-2 node precompute: E2[n] = b2a + h[n]@W2a[0:32] + pos[n]@W2a[32:35];
// also resets agg row for reuse by layer 2 (each thread owns its row).
__global__ __launch_bounds__(256) void k_pre2(const float* __restrict__ pos,
                                              unsigned* __restrict__ agg,
                                              const float* __restrict__ W2a,
                                              const float* __restrict__ b2a,
                                              float* __restrict__ E2) {
    int n = blockIdx.x * 256 + threadIdx.x;
    if (n >= NN) return;
    float h[H];
    uint4* A4 = (uint4*)(agg + (size_t)n * H);
#pragma unroll
    for (int r = 0; r < 8; r++) {
        uint4 u = A4[r];
        h[4 * r + 0] = decf(u.x);
        h[4 * r + 1] = decf(u.y);
        h[4 * r + 2] = decf(u.z);
        h[4 * r + 3] = decf(u.w);
        A4[r] = make_uint4(0x80000000u, 0x80000000u, 0x80000000u, 0x80000000u);
    }
    float p0 = pos[3 * n], p1 = pos[3 * n + 1], p2 = pos[3 * n + 2];
    float ev[H];
#pragma unroll
    for (int k = 0; k < H; k++) {
        float v = b2a[k];
        v = fmaf(p0, W2a[32 * H + k], v);
        v = fmaf(p1, W2a[33 * H + k], v);
        v = fmaf(p2, W2a[34 * H + k], v);
        ev[k] = v;
    }
#pragma unroll
    for (int j = 0; j < H; j++) {
        float hj = h[j];
#pragma unroll
        for (int k = 0; k < H; k++) ev[k] = fmaf(hj, W2a[j * H + k], ev[k]);
    }
    float4* E4 = (float4*)(E2 + (size_t)n * H);
#pragma unroll
    for (int r = 0; r < 8; r++)
        E4[r] = make_float4(ev[4 * r], ev[4 * r + 1], ev[4 * r + 2], ev[4 * r + 3]);
}

// Layer-2 edge kernel: same two-half structure. Per half, gather the full E2
// row (j is the input dim -> both halves need all 32), dst-term recomputed
// inline. Live set ~50 VGPR.
__global__ __launch_bounds__(256) void k_edge2(const unsigned* __restrict__ srcS,
                                               const unsigned* __restrict__ ends,
                                               const unsigned* __restrict__ chunk_node,
                                               const float* __restrict__ pos,
                                               const float* __restrict__ E2,
                                               const float* __restrict__ W2a,
                                               const float* __restrict__ W2b,
                                               const float* __restrict__ b2b,
                                               unsigned* __restrict__ agg) {
    int gid = blockIdx.x * 256 + threadIdx.x;
    if (gid >= NCH) return;
    unsigned base = (unsigned)gid * CE;
#pragma unroll 1
    for (int hb = 0; hb < 2; hb++) {
        int cur = (int)chunk_node[gid];
        unsigned end_cur = ends[cur];
        float pd0 = pos[3 * cur], pd1 = pos[3 * cur + 1], pd2 = pos[3 * cur + 2];
        float macc[16];
#pragma unroll
        for (int k = 0; k < 16; k++) macc[k] = 0.f;
#pragma unroll 1
        for (int c = 0; c < CE; c++) {
            unsigned e = base + c;
            if (e >= end_cur) {
                flush_half(agg, cur, hb, macc);
                do { cur++; end_cur = ends[cur]; } while (e >= end_cur);
                pd0 = pos[3 * cur]; pd1 = pos[3 * cur + 1]; pd2 = pos[3 * cur + 2];
#pragma unroll
                for (int k = 0; k < 16; k++) macc[k] = 0.f;
            }
            int s = (int)srcS[e];
            const float4* er = (const float4*)(E2 + (size_t)s * H);
            float m[16];
#pragma unroll
            for (int k = 0; k < 16; k++) m[k] = b2b[hb * 16 + k];
#pragma unroll
            for (int r = 0; r < 8; r++) {
                float4 e4 = er[r];
#pragma unroll
                for (int q = 0; q < 4; q++) {
                    int j = 4 * r + q;
                    float ej = (q == 0) ? e4.x : (q == 1) ? e4.y : (q == 2) ? e4.z : e4.w;
                    float w = fmaf(pd0, W2a[32 * H + j],
                              fmaf(pd1, W2a[33 * H + j], pd2 * W2a[34 * H + j]));
                    float t = fmaxf(ej - w, 0.f);
#pragma unroll
                    for (int k = 0; k < 16; k++)
                        m[k] = fmaf(t, W2b[j * H + hb * 16 + k], m[k]);
                }
            }
#pragma unroll
            for (int k = 0; k < 16; k++) macc[k] = fmaxf(macc[k], m[k]);
        }
        flush_half(agg, cur, hb, macc);
    }
}

// Graph max-pool (encoded domain; max commutes with monotone encoding).
__global__ __launch_bounds__(256) void k_pool(const unsigned* __restrict__ agg,
                                              const int* __restrict__ batch,
                                              unsigned* __restrict__ g) {
    int n = blockIdx.x * 256 + threadIdx.x;
    if (n >= NN) return;
    int bidx = batch[n];
    unsigned* gb = g + (size_t)bidx * H;
    const uint4* A4 = (const uint4*)(agg + (size_t)n * H);
#pragma unroll
    for (int r = 0; r < 8; r++) {
        uint4 v = A4[r];
        uint4 c = ((const uint4*)gb)[r];
        if (v.x > c.x) atomicMax(gb + 4 * r + 0, v.x);
        if (v.y > c.y) atomicMax(gb + 4 * r + 1, v.y);
        if (v.z > c.z) atomicMax(gb + 4 * r + 2, v.z);
        if (v.w > c.w) atomicMax(gb + 4 * r + 3, v.w);
    }
}

__global__ __launch_bounds__(256) void k_out(const unsigned* __restrict__ g,
                                             const float* __restrict__ Wout,
                                             const float* __restrict__ bout,
                                             float* __restrict__ out) {
    int bidx = threadIdx.x;  // one block of 256
    float acc = bout[0];
#pragma unroll
    for (int k = 0; k < H; k++) acc = fmaf(decf(g[bidx * H + k]), Wout[k], acc);
    out[bidx] = acc;
}

extern "C" void kernel_launch(void* const* d_in, const int* in_sizes, int n_in,
                              void* d_out, int out_size, void* d_ws, size_t ws_size,
                              hipStream_t stream) {
    const float* pos  = (const float*)d_in[0];
    const int* src    = (const int*)d_in[1];
    const int* dst    = src + NE;
    const int* batch  = (const int*)d_in[2];
    const float* W1a  = (const float*)d_in[3];
    const float* b1a  = (const float*)d_in[4];
    const float* W1b  = (const float*)d_in[5];
    const float* b1b  = (const float*)d_in[6];
    const float* W2a  = (const float*)d_in[7];
    const float* b2a  = (const float*)d_in[8];
    const float* W2b  = (const float*)d_in[9];
    const float* b2b  = (const float*)d_in[10];
    const float* Wout = (const float*)d_in[11];
    const float* bout = (const float*)d_in[12];
    float* out = (float*)d_out;

    const size_t SZ = (size_t)NN * H;  // 3.2M words
    unsigned* agg        = (unsigned*)d_ws;          // 12.8 MB
    float*    E2         = (float*)d_ws + SZ;        // 12.8 MB (aliased pre-edge1)
    unsigned* srcS       = (unsigned*)d_ws + 2 * SZ; // 12.8 MB (dst-sorted src ids)
    unsigned* g          = (unsigned*)d_ws + 3 * SZ; // 32 KB
    unsigned* ends       = g + NG * H;               // 400 KB (CSR run ends)
    unsigned* chunk_node = ends + NN;                // 1.6 MB (first dst per chunk)
    unsigned* bsum       = chunk_node + NCH;         // scan partials
    unsigned* bpre       = bsum + SB + 1;
    // Sort-phase temporaries aliased into E2's space (dead before k_pre2 writes):
    unsigned* hist    = (unsigned*)E2;
    unsigned* pre     = hist + NN;
    unsigned* cursors = pre + NN;

    const int EDGE_BLOCKS  = NE / 256;          // 12500
    const int INIT_BLOCKS  = (NN * H) / 256;    // 12500
    const int NODE_BLOCKS  = SB;                // 391
    const int CHUNK_BLOCKS = (NCH + 255) / 256; // 1563

    k_init<<<INIT_BLOCKS, 256, 0, stream>>>(agg, g, hist);
    k_hist<<<EDGE_BLOCKS, 256, 0, stream>>>(dst, hist);
    k_scan1<<<NODE_BLOCKS, 256, 0, stream>>>(hist, pre, bsum);
    k_scan2<<<1, 512, 0, stream>>>(bsum, bpre);
    k_scan3<<<NODE_BLOCKS, 256, 0, stream>>>(pre, bpre, hist, cursors, ends);
    k_scatter<<<EDGE_BLOCKS, 256, 0, stream>>>(src, dst, cursors, srcS);
    k_chunks<<<CHUNK_BLOCKS, 256, 0, stream>>>(ends, chunk_node);
    k_edge1<<<CHUNK_BLOCKS, 256, 0, stream>>>(srcS, ends, chunk_node, pos,
                                              W1a, b1a, W1b, b1b, agg);
    k_pre2<<<NODE_BLOCKS, 256, 0, stream>>>(pos, agg, W2a, b2a, E2);
    k_edge2<<<CHUNK_BLOCKS, 256, 0, stream>>>(srcS, ends, chunk_node, pos, E2,
                                              W2a, W2b, b2b, agg);
    k_pool<<<NODE_BLOCKS, 256, 0, stream>>>(agg, batch, g);
    k_out<<<1, 256, 0, stream>>>(g, Wout, bout, out);
}

// Round 7
// 1800.081 us; speedup vs baseline: 1.1539x; 1.0370x over previous
//
#include <hip/hip_runtime.h>

#define NN 100000
#define NE 3200000
#define NG 256
#define H 32
#define CE 8                     // edges per thread chunk
#define NCH (NE / CE)            // 400000 chunks
#define SB ((NN + 255) / 256)    // 391 scan blocks

// Monotone bijection float -> u32 (order-preserving), so u32 max == float max.
__device__ __forceinline__ unsigned encf(float f) {
    unsigned u = __float_as_uint(f);
    return (u & 0x80000000u) ? ~u : (u | 0x80000000u);
}
__device__ __forceinline__ float decf(unsigned u) {
    return __uint_as_float((u & 0x80000000u) ? (u & 0x7fffffffu) : ~u);
}

// Flush a 32-wide register run-max to global agg (enc domain, test-before-atomic).
// agg starts at enc(0): values <=0 never pass the test (folds relu + neginf fill).
__device__ __forceinline__ void flush_row(unsigned* __restrict__ agg, int node,
                                          const float* m) {
    unsigned* ag = agg + (size_t)node * H;
#pragma unroll
    for (int r = 0; r < 8; r++) {
        uint4 c = ((const uint4*)ag)[r];
        unsigned v0 = encf(m[4 * r + 0]);
        unsigned v1 = encf(m[4 * r + 1]);
        unsigned v2 = encf(m[4 * r + 2]);
        unsigned v3 = encf(m[4 * r + 3]);
        if (v0 > c.x) atomicMax(ag + 4 * r + 0, v0);
        if (v1 > c.y) atomicMax(ag + 4 * r + 1, v1);
        if (v2 > c.z) atomicMax(ag + 4 * r + 2, v2);
        if (v3 > c.w) atomicMax(ag + 4 * r + 3, v3);
    }
}

// init agg=enc(0), g=enc(0), hist=0. Grid covers NN*H = 3.2M.
__global__ __launch_bounds__(256) void k_init(unsigned* __restrict__ agg,
                                              unsigned* __restrict__ g,
                                              unsigned* __restrict__ hist) {
    int i = blockIdx.x * 256 + threadIdx.x;
    agg[i] = 0x80000000u;
    if (i < NG * H) g[i] = 0x80000000u;
    if (i < NN) hist[i] = 0u;
}

// Pack transposed weight columns for streaming access:
//   Wt[j][8]  = { b1a[j], W1a[0][j]..W1a[5][j], 0 }        (layer-1 t weights)
//   WpT[j][4] = { W2a[32][j], W2a[33][j], W2a[34][j], 0 }  (layer-2 dst-term)
__global__ __launch_bounds__(64) void k_packw(const float* __restrict__ W1a,
                                              const float* __restrict__ b1a,
                                              const float* __restrict__ W2a,
                                              float* __restrict__ Wt,
                                              float* __restrict__ WpT) {
    int j = threadIdx.x;
    if (j >= H) return;
    Wt[8 * j] = b1a[j];
#pragma unroll
    for (int i = 0; i < 6; i++) Wt[8 * j + 1 + i] = W1a[i * H + j];
    Wt[8 * j + 7] = 0.f;
#pragma unroll
    for (int i = 0; i < 3; i++) WpT[4 * j + i] = W2a[(32 + i) * H + j];
    WpT[4 * j + 3] = 0.f;
}

__global__ __launch_bounds__(256) void k_hist(const int* __restrict__ dst,
                                              unsigned* __restrict__ hist) {
    int e = blockIdx.x * 256 + threadIdx.x;   // grid covers exactly NE
    atomicAdd(&hist[dst[e]], 1u);
}

// Block-level exclusive scan (Hillis-Steele in LDS), 256 elems/block.
__global__ __launch_bounds__(256) void k_scan1(const unsigned* __restrict__ hist,
                                               unsigned* __restrict__ pre,
                                               unsigned* __restrict__ bsum) {
    __shared__ unsigned sd[256];
    int tid = threadIdx.x;
    int i = blockIdx.x * 256 + tid;
    unsigned v = (i < NN) ? hist[i] : 0u;
    sd[tid] = v;
    __syncthreads();
    for (int off = 1; off < 256; off <<= 1) {
        unsigned t = (tid >= off) ? sd[tid - off] : 0u;
        __syncthreads();
        sd[tid] += t;
        __syncthreads();
    }
    if (i < NN) pre[i] = sd[tid] - v;
    if (tid == 255) bsum[blockIdx.x] = sd[255];
}

__global__ __launch_bounds__(512) void k_scan2(const unsigned* __restrict__ bsum,
                                               unsigned* __restrict__ bpre) {
    __shared__ unsigned sd[512];
    int t = threadIdx.x;
    unsigned v = (t < SB) ? bsum[t] : 0u;
    sd[t] = v;
    __syncthreads();
    for (int off = 1; off < 512; off <<= 1) {
        unsigned x = (t >= off) ? sd[t - off] : 0u;
        __syncthreads();
        sd[t] += x;
        __syncthreads();
    }
    if (t < SB) bpre[t] = sd[t] - v;
}

// cursors[i] = global exclusive prefix (scatter cursor); ends[i] = prefix+count.
__global__ __launch_bounds__(256) void k_scan3(const unsigned* __restrict__ pre,
                                               const unsigned* __restrict__ bpre,
                                               const unsigned* __restrict__ hist,
                                               unsigned* __restrict__ cursors,
                                               unsigned* __restrict__ ends) {
    int i = blockIdx.x * 256 + threadIdx.x;
    if (i < NN) {
        unsigned o = pre[i] + bpre[blockIdx.x];
        cursors[i] = o;
        ends[i] = o + hist[i];
    }
}

// Scatter src ids into dst-sorted order (order within a run is nondeterministic
// but max-reduction is order-free).
__global__ __launch_bounds__(256) void k_scatter(const int* __restrict__ src,
                                                 const int* __restrict__ dst,
                                                 unsigned* __restrict__ cursors,
                                                 unsigned* __restrict__ srcS) {
    int e = blockIdx.x * 256 + threadIdx.x;   // grid covers exactly NE
    int d = dst[e];
    unsigned slot = atomicAdd(&cursors[d], 1u);
    srcS[slot] = (unsigned)src[e];
}

// chunk_node[c] = dst node owning edge c*CE = smallest n with ends[n] > c*CE.
__global__ __launch_bounds__(256) void k_chunks(const unsigned* __restrict__ ends,
                                                unsigned* __restrict__ chunk_node) {
    int c = blockIdx.x * 256 + threadIdx.x;
    if (c >= NCH) return;
    unsigned target = (unsigned)c * CE;
    int lo = 0, hi = NN - 1;
    while (lo < hi) {
        int mid = (lo + hi) >> 1;
        if (ends[mid] <= target) lo = mid + 1; else hi = mid;
    }
    chunk_node[c] = (unsigned)lo;
}

// Layer-1 edge kernel. 2-edge tiles, full 32-wide output in one pass.
// amdgpu_waves_per_eu(4,4): allocator targets exactly 4 waves/SIMD -> up to
// 128 VGPR with NO spill. pd0..2 always tracks pos[cur] (updated in BOTH
// boundary branches; per-edge values read between the two advances).
__global__ __launch_bounds__(256) __attribute__((amdgpu_waves_per_eu(4, 4)))
void k_edge1(const unsigned* __restrict__ srcS,
             const unsigned* __restrict__ ends,
             const unsigned* __restrict__ chunk_node,
             const float* __restrict__ pos,
             const float* __restrict__ Wt,
             const float* __restrict__ W1b,
             const float* __restrict__ b1b,
             unsigned* __restrict__ agg) {
    int gid = blockIdx.x * 256 + threadIdx.x;
    if (gid >= NCH) return;
    unsigned base = (unsigned)gid * CE;
    int cur = (int)chunk_node[gid];
    unsigned end_cur = ends[cur];
    float pd0 = pos[3 * cur], pd1 = pos[3 * cur + 1], pd2 = pos[3 * cur + 2];
    float macc[H];
#pragma unroll
    for (int k = 0; k < H; k++) macc[k] = 0.f;
#pragma unroll 1
    for (int tile = 0; tile < 4; tile++) {
        unsigned eA = base + tile * 2, eB = eA + 1;
        int s0 = (int)srcS[eA], s1 = (int)srcS[eB];
        bool fA = (eA >= end_cur);
        int fdA = cur;
        if (fA) {
            do { cur++; end_cur = ends[cur]; } while (eA >= end_cur);
            pd0 = pos[3 * cur]; pd1 = pos[3 * cur + 1]; pd2 = pos[3 * cur + 2];
        }
        float psA0 = pos[3 * s0], psA1 = pos[3 * s0 + 1], psA2 = pos[3 * s0 + 2];
        float evA0 = psA0 - pd0, evA1 = psA1 - pd1, evA2 = psA2 - pd2;
        bool fB = (eB >= end_cur);
        int fdB = cur;
        if (fB) {
            do { cur++; end_cur = ends[cur]; } while (eB >= end_cur);
            pd0 = pos[3 * cur]; pd1 = pos[3 * cur + 1]; pd2 = pos[3 * cur + 2];
        }
        float psB0 = pos[3 * s1], psB1 = pos[3 * s1 + 1], psB2 = pos[3 * s1 + 2];
        float evB0 = psB0 - pd0, evB1 = psB1 - pd1, evB2 = psB2 - pd2;

        float m0[H], m1[H];
#pragma unroll
        for (int k = 0; k < H; k++) { m0[k] = b1b[k]; m1[k] = b1b[k]; }
#pragma unroll 1
        for (int j = 0; j < H; j++) {       // rolled: tiny I$, scalar-load weights
            const float* wr = Wt + (j << 3);
            float w0 = wr[0], w1 = wr[1], w2 = wr[2], w3 = wr[3];
            float w4 = wr[4], w5 = wr[5], w6 = wr[6];
            float tA = w0;
            tA = fmaf(psA0, w1, tA); tA = fmaf(psA1, w2, tA); tA = fmaf(psA2, w3, tA);
            tA = fmaf(evA0, w4, tA); tA = fmaf(evA1, w5, tA); tA = fmaf(evA2, w6, tA);
            tA = fmaxf(tA, 0.f);
            float tB = w0;
            tB = fmaf(psB0, w1, tB); tB = fmaf(psB1, w2, tB); tB = fmaf(psB2, w3, tB);
            tB = fmaf(evB0, w4, tB); tB = fmaf(evB1, w5, tB); tB = fmaf(evB2, w6, tB);
            tB = fmaxf(tB, 0.f);
            const float* br = W1b + (j << 5);
#pragma unroll
            for (int k = 0; k < H; k++) {
                float b = br[k];
                m0[k] = fmaf(tA, b, m0[k]);
                m1[k] = fmaf(tB, b, m1[k]);
            }
        }
        if (fA) {
            flush_row(agg, fdA, macc);
#pragma unroll
            for (int k = 0; k < H; k++) macc[k] = 0.f;
        }
#pragma unroll
        for (int k = 0; k < H; k++) macc[k] = fmaxf(macc[k], m0[k]);
        if (fB) {
            flush_row(agg, fdB, macc);
#pragma unroll
            for (int k = 0; k < H; k++) macc[k] = 0.f;
        }
#pragma unroll
        for (int k = 0; k < H; k++) macc[k] = fmaxf(macc[k], m1[k]);
    }
    flush_row(agg, cur, macc);
}

// Layer-2 node precompute: E2[n] = b2a + h[n]@W2a[0:32] + pos[n]@W2a[32:35];
// also resets agg row for reuse by layer 2 (each thread owns its row).
__global__ __launch_bounds__(256) void k_pre2(const float* __restrict__ pos,
                                              unsigned* __restrict__ agg,
                                              const float* __restrict__ W2a,
                                              const float* __restrict__ b2a,
                                              float* __restrict__ E2) {
    int n = blockIdx.x * 256 + threadIdx.x;
    if (n >= NN) return;
    float h[H];
    uint4* A4 = (uint4*)(agg + (size_t)n * H);
#pragma unroll
    for (int r = 0; r < 8; r++) {
        uint4 u = A4[r];
        h[4 * r + 0] = decf(u.x);
        h[4 * r + 1] = decf(u.y);
        h[4 * r + 2] = decf(u.z);
        h[4 * r + 3] = decf(u.w);
        A4[r] = make_uint4(0x80000000u, 0x80000000u, 0x80000000u, 0x80000000u);
    }
    float p0 = pos[3 * n], p1 = pos[3 * n + 1], p2 = pos[3 * n + 2];
    float ev[H];
#pragma unroll
    for (int k = 0; k < H; k++) {
        float v = b2a[k];
        v = fmaf(p0, W2a[32 * H + k], v);
        v = fmaf(p1, W2a[33 * H + k], v);
        v = fmaf(p2, W2a[34 * H + k], v);
        ev[k] = v;
    }
#pragma unroll
    for (int j = 0; j < H; j++) {
        float hj = h[j];
#pragma unroll
        for (int k = 0; k < H; k++) ev[k] = fmaf(hj, W2a[j * H + k], ev[k]);
    }
    float4* E4 = (float4*)(E2 + (size_t)n * H);
#pragma unroll
    for (int r = 0; r < 8; r++)
        E4[r] = make_float4(ev[4 * r], ev[4 * r + 1], ev[4 * r + 2], ev[4 * r + 3]);
}

// Layer-2 edge kernel. 2-edge tiles, 32-wide single pass, E2 rows streamed in
// 8-float chunks. FIX vs round 6: pd0..2 always tracks pos[cur] (updated in
// BOTH boundary branches); per-edge snapshots pa/pb taken after each advance,
// so wA/wB never use a stale dst position.
__global__ __launch_bounds__(256) __attribute__((amdgpu_waves_per_eu(3, 3)))
void k_edge2(const unsigned* __restrict__ srcS,
             const unsigned* __restrict__ ends,
             const unsigned* __restrict__ chunk_node,
             const float* __restrict__ pos,
             const float* __restrict__ E2,
             const float* __restrict__ WpT,
             const float* __restrict__ W2b,
             const float* __restrict__ b2b,
             unsigned* __restrict__ agg) {
    int gid = blockIdx.x * 256 + threadIdx.x;
    if (gid >= NCH) return;
    unsigned base = (unsigned)gid * CE;
    int cur = (int)chunk_node[gid];
    unsigned end_cur = ends[cur];
    float pd0 = pos[3 * cur], pd1 = pos[3 * cur + 1], pd2 = pos[3 * cur + 2];
    float macc[H];
#pragma unroll
    for (int k = 0; k < H; k++) macc[k] = 0.f;
#pragma unroll 1
    for (int tile = 0; tile < 4; tile++) {
        unsigned eA = base + tile * 2, eB = eA + 1;
        int s0 = (int)srcS[eA], s1 = (int)srcS[eB];
        bool fA = (eA >= end_cur);
        int fdA = cur;
        if (fA) {
            do { cur++; end_cur = ends[cur]; } while (eA >= end_cur);
            pd0 = pos[3 * cur]; pd1 = pos[3 * cur + 1]; pd2 = pos[3 * cur + 2];
        }
        float pa0 = pd0, pa1 = pd1, pa2 = pd2;   // dst position for edge A
        bool fB = (eB >= end_cur);
        int fdB = cur;
        if (fB) {
            do { cur++; end_cur = ends[cur]; } while (eB >= end_cur);
            pd0 = pos[3 * cur]; pd1 = pos[3 * cur + 1]; pd2 = pos[3 * cur + 2];
        }
        float pb0 = pd0, pb1 = pd1, pb2 = pd2;   // dst position for edge B

        const float* r0 = E2 + (size_t)s0 * H;
        const float* r1 = E2 + (size_t)s1 * H;
        float m0[H], m1[H];
#pragma unroll
        for (int k = 0; k < H; k++) { m0[k] = b2b[k]; m1[k] = b2b[k]; }
#pragma unroll 1
        for (int cc = 0; cc < 4; cc++) {    // 8-j chunks; er regs statically indexed
            float4 a0 = ((const float4*)(r0 + cc * 8))[0];
            float4 a1 = ((const float4*)(r0 + cc * 8))[1];
            float4 c0 = ((const float4*)(r1 + cc * 8))[0];
            float4 c1 = ((const float4*)(r1 + cc * 8))[1];
            float ea[8] = {a0.x, a0.y, a0.z, a0.w, a1.x, a1.y, a1.z, a1.w};
            float eb[8] = {c0.x, c0.y, c0.z, c0.w, c1.x, c1.y, c1.z, c1.w};
            const float* wp = WpT + (cc << 5);
#pragma unroll
            for (int jj = 0; jj < 8; jj++) {
                float q0 = wp[jj * 4], q1 = wp[jj * 4 + 1], q2 = wp[jj * 4 + 2];
                float wA = fmaf(pa0, q0, fmaf(pa1, q1, pa2 * q2));
                float wB = fmaf(pb0, q0, fmaf(pb1, q1, pb2 * q2));
                float tA = fmaxf(ea[jj] - wA, 0.f);
                float tB = fmaxf(eb[jj] - wB, 0.f);
                const float* br = W2b + ((cc * 8 + jj) << 5);
#pragma unroll
                for (int k = 0; k < H; k++) {
                    float b = br[k];
                    m0[k] = fmaf(tA, b, m0[k]);
                    m1[k] = fmaf(tB, b, m1[k]);
                }
            }
        }
        if (fA) {
            flush_row(agg, fdA, macc);
#pragma unroll
            for (int k = 0; k < H; k++) macc[k] = 0.f;
        }
#pragma unroll
        for (int k = 0; k < H; k++) macc[k] = fmaxf(macc[k], m0[k]);
        if (fB) {
            flush_row(agg, fdB, macc);
#pragma unroll
            for (int k = 0; k < H; k++) macc[k] = 0.f;
        }
#pragma unroll
        for (int k = 0; k < H; k++) macc[k] = fmaxf(macc[k], m1[k]);
    }
    flush_row(agg, cur, macc);
}

// Graph max-pool (encoded domain; max commutes with monotone encoding).
__global__ __launch_bounds__(256) void k_pool(const unsigned* __restrict__ agg,
                                              const int* __restrict__ batch,
                                              unsigned* __restrict__ g) {
    int n = blockIdx.x * 256 + threadIdx.x;
    if (n >= NN) return;
    int bidx = batch[n];
    unsigned* gb = g + (size_t)bidx * H;
    const uint4* A4 = (const uint4*)(agg + (size_t)n * H);
#pragma unroll
    for (int r = 0; r < 8; r++) {
        uint4 v = A4[r];
        uint4 c = ((const uint4*)gb)[r];
        if (v.x > c.x) atomicMax(gb + 4 * r + 0, v.x);
        if (v.y > c.y) atomicMax(gb + 4 * r + 1, v.y);
        if (v.z > c.z) atomicMax(gb + 4 * r + 2, v.z);
        if (v.w > c.w) atomicMax(gb + 4 * r + 3, v.w);
    }
}

__global__ __launch_bounds__(256) void k_out(const unsigned* __restrict__ g,
                                             const float* __restrict__ Wout,
                                             const float* __restrict__ bout,
                                             float* __restrict__ out) {
    int bidx = threadIdx.x;  // one block of 256
    float acc = bout[0];
#pragma unroll
    for (int k = 0; k < H; k++) acc = fmaf(decf(g[bidx * H + k]), Wout[k], acc);
    out[bidx] = acc;
}

extern "C" void kernel_launch(void* const* d_in, const int* in_sizes, int n_in,
                              void* d_out, int out_size, void* d_ws, size_t ws_size,
                              hipStream_t stream) {
    const float* pos  = (const float*)d_in[0];
    const int* src    = (const int*)d_in[1];
    const int* dst    = src + NE;
    const int* batch  = (const int*)d_in[2];
    const float* W1a  = (const float*)d_in[3];
    const float* b1a  = (const float*)d_in[4];
    const float* W1b  = (const float*)d_in[5];
    const float* b1b  = (const float*)d_in[6];
    const float* W2a  = (const float*)d_in[7];
    const float* b2a  = (const float*)d_in[8];
    const float* W2b  = (const float*)d_in[9];
    const float* b2b  = (const float*)d_in[10];
    const float* Wout = (const float*)d_in[11];
    const float* bout = (const float*)d_in[12];
    float* out = (float*)d_out;

    const size_t SZ = (size_t)NN * H;  // 3.2M words
    unsigned* agg        = (unsigned*)d_ws;          // 12.8 MB
    float*    E2         = (float*)d_ws + SZ;        // 12.8 MB (aliased pre-edge1)
    unsigned* srcS       = (unsigned*)d_ws + 2 * SZ; // 12.8 MB (dst-sorted src ids)
    unsigned* g          = (unsigned*)d_ws + 3 * SZ; // 32 KB
    unsigned* ends       = g + NG * H;               // 400 KB (CSR run ends)
    unsigned* chunk_node = ends + NN;                // 1.6 MB (first dst per chunk)
    unsigned* bsum       = chunk_node + NCH;         // scan partials
    unsigned* bpre       = bsum + SB + 1;
    float*    Wt         = (float*)(bpre + SB + 1);  // 256 floats packed t-weights
    float*    WpT        = Wt + 8 * H;               // 128 floats packed dst-term
    // Sort-phase temporaries aliased into E2's space (dead before k_pre2 writes):
    unsigned* hist    = (unsigned*)E2;
    unsigned* pre     = hist + NN;
    unsigned* cursors = pre + NN;

    const int EDGE_BLOCKS  = NE / 256;          // 12500
    const int INIT_BLOCKS  = (NN * H) / 256;    // 12500
    const int NODE_BLOCKS  = SB;                // 391
    const int CHUNK_BLOCKS = (NCH + 255) / 256; // 1563

    k_init<<<INIT_BLOCKS, 256, 0, stream>>>(agg, g, hist);
    k_packw<<<1, 64, 0, stream>>>(W1a, b1a, W2a, Wt, WpT);
    k_hist<<<EDGE_BLOCKS, 256, 0, stream>>>(dst, hist);
    k_scan1<<<NODE_BLOCKS, 256, 0, stream>>>(hist, pre, bsum);
    k_scan2<<<1, 512, 0, stream>>>(bsum, bpre);
    k_scan3<<<NODE_BLOCKS, 256, 0, stream>>>(pre, bpre, hist, cursors, ends);
    k_scatter<<<EDGE_BLOCKS, 256, 0, stream>>>(src, dst, cursors, srcS);
    k_chunks<<<CHUNK_BLOCKS, 256, 0, stream>>>(ends, chunk_node);
    k_edge1<<<CHUNK_BLOCKS, 256, 0, stream>>>(srcS, ends, chunk_node, pos,
                                              Wt, W1b, b1b, agg);
    k_pre2<<<NODE_BLOCKS, 256, 0, stream>>>(pos, agg, W2a, b2a, E2);
    k_edge2<<<CHUNK_BLOCKS, 256, 0, stream>>>(srcS, ends, chunk_node, pos, E2,
                                              WpT, W2b, b2b, agg);
    k_pool<<<NODE_BLOCKS, 256, 0, stream>>>(agg, batch, g);
    k_out<<<1, 256, 0, stream>>>(g, Wout, bout, out);
}